// Round 6
// baseline (227.976 us; speedup 1.0000x reference)
//
#include <hip/hip_runtime.h>
#include <hip/hip_bf16.h>

typedef __hip_bfloat16 bf16;
typedef short bf16x8 __attribute__((ext_vector_type(8)));
typedef float f32x4 __attribute__((ext_vector_type(4)));

#define HT 16384   // bf16 half-tile bytes: 128 rows x 64 cols

__device__ __forceinline__ void gload16(const void* g, void* l) {
    __builtin_amdgcn_global_load_lds(
        (const __attribute__((address_space(1))) void*)g,
        (__attribute__((address_space(3))) void*)l, 16, 0, 0);
}

// Stage one 128x64 bf16 half-tile into LDS slot slotIdx (16 KiB units).
// Linear LDS dest; source pre-swizzled with involution chunk ^= row&7.
__device__ __forceinline__ void stage_half(char* lds, const bf16* src, int ld,
                                           int rowbase, int k0, int slotIdx,
                                           int tid)
{
    char* dst = lds + (size_t)slotIdx * HT + tid * 16;
    const int sub = tid >> 3;
    const int cb  = ((tid & 7) ^ (sub & 7)) << 4;
    #pragma unroll
    for (int p = 0; p < 2; ++p) {
        const int row = p * 64 + sub;
        const char* g = (const char*)(src + (size_t)(rowbase + row) * ld + k0) + cb;
        gload16(g, dst + p * 8192);
    }
}

// read one MFMA A/B fragment (8 bf16 = 16B) with the read-side swizzle
__device__ __forceinline__ bf16x8 ldsfrag(const char* lds, int slotIdx,
                                          int row, int ks, int cb0)
{
    return *(const bf16x8*)(lds + (size_t)slotIdx * HT
                            + row * 128 + (cb0 ^ (ks << 6)));
}

__device__ __forceinline__ float bf2f(short s) {
    union { float f; unsigned u; } c;
    c.u = ((unsigned)(unsigned short)s) << 16;
    return c.f;
}

// ====== fused projection: [24576,1024]bf16 = f32[q;k;v] @ Wt^T-form ======
// BM=256 BN=128 BK=64, 8 waves 4Mx2N (wave tile 64x64). LDS slots per buf:
// A0=0 A1=1 B=2 (bf16, 16K each), dbuf -> 96 KiB. A arrives via reg-staging:
// f32 loads issued at t.ph0 for tile t+2, cvt+swizzled ds_write at (t+1).ph0
// (4-phase latency cover). B via gload_lds with counted vmcnt (never 0).
__launch_bounds__(512, 2)
__global__ void proj_fused(const float* __restrict__ q, const float* __restrict__ k,
                           const float* __restrict__ v, const bf16* __restrict__ B,
                           bf16* __restrict__ C)
{
    extern __shared__ char lds[];
    // chunked bijective XCD swizzle over 768 blocks (96 per XCD)
    const int orig = blockIdx.y * 8 + blockIdx.x;
    const int wk = (orig & 7) * 96 + (orig >> 3);
    const int bi = wk >> 3, bj = wk & 7;               // bi 0..95, bj 0..7
    const int brow = bi * 256, bcol = bj * 128;
    const float* Asrc = (bi < 32) ? q : (bi < 64) ? k : v;
    const int arow = (bi & 31) * 256;

    const int tid  = threadIdx.x;
    const int lane = tid & 63;
    const int w    = tid >> 6;
    const int wm   = w >> 1, wn = w & 1;               // 4M x 2N
    const int fr   = lane & 15, fq = lane >> 4;
    const int cb0  = ((fr & 7) ^ fq) << 4;
    const int slotA = wm >> 1;
    const int rA    = (wm & 1) * 64;
    const int rB    = wn * 64;
    const int NT    = 16;                              // K=1024/64

    // staging-thread mapping: half sh (128 rows), row srow, 64B part spart
    const int sh    = tid >> 8;
    const int ss    = tid & 255;
    const int srow  = ss >> 1;
    const int spart = ss & 1;
    const float* gbase = Asrc + (size_t)(arow + sh * 128 + srow) * 1024 + spart * 32;

    f32x4 acc[4][4] = {};
    bf16x8 af[4][2], bv[4][2];
    float4 ld[8];

#define LOADA(kk)                                                             \
    _Pragma("unroll") for (int j = 0; j < 8; ++j)                             \
        ld[j] = *(const float4*)(gbase + (kk) + j * 4);

#define WRITEA(nb)                                                            \
    {                                                                         \
        char* hbase = lds + (size_t)((nb) * 3 + sh) * HT + srow * 128;        \
        _Pragma("unroll") for (int c = 0; c < 4; ++c) {                       \
            union { short h[8]; bf16x8 v8; } o_;                              \
            float4 a_ = ld[2 * c], b_ = ld[2 * c + 1];                        \
            bf16 t0 = __float2bfloat16(a_.x), t1 = __float2bfloat16(a_.y),    \
                 t2 = __float2bfloat16(a_.z), t3 = __float2bfloat16(a_.w),    \
                 t4 = __float2bfloat16(b_.x), t5 = __float2bfloat16(b_.y),    \
                 t6 = __float2bfloat16(b_.z), t7 = __float2bfloat16(b_.w);    \
            o_.h[0] = *(short*)&t0; o_.h[1] = *(short*)&t1;                   \
            o_.h[2] = *(short*)&t2; o_.h[3] = *(short*)&t3;                   \
            o_.h[4] = *(short*)&t4; o_.h[5] = *(short*)&t5;                   \
            o_.h[6] = *(short*)&t6; o_.h[7] = *(short*)&t7;                   \
            *(bf16x8*)(hbase + (((spart * 4 + c) ^ (srow & 7)) << 4)) = o_.v8;\
        }                                                                     \
    }

    // prologue: A(0) via regs (full wait), B(0), A(1) loads, B(1)
    LOADA(0)
    asm volatile("s_waitcnt vmcnt(0)" ::: "memory");
    WRITEA(0)
    stage_half(lds, B, 1024, bcol, 0, 2, tid);
    LOADA(64)
    stage_half(lds, B, 1024, bcol, 64, 5, tid);
    asm volatile("s_waitcnt vmcnt(10)" ::: "memory");   // B(0) landed
    asm volatile("s_waitcnt lgkmcnt(0)" ::: "memory");  // A(0) writes visible
    __builtin_amdgcn_s_barrier();

#define QUAD2(m0, n0)                                                         \
    _Pragma("unroll") for (int dm = 0; dm < 2; ++dm)                          \
    _Pragma("unroll") for (int dn = 0; dn < 2; ++dn)                          \
    _Pragma("unroll") for (int ks = 0; ks < 2; ++ks)                          \
        acc[(m0)+dm][(n0)+dn] = __builtin_amdgcn_mfma_f32_16x16x32_bf16(      \
            af[(m0)+dm][ks], bv[(n0)+dn][ks], acc[(m0)+dm][(n0)+dn], 0, 0, 0);

    for (int t = 0; t < NT; ++t) {
        const int buf = t & 1, nbuf = buf ^ 1;
        const int k2 = min(t + 2, NT - 1) << 6;

        // ph0: read af01+bv01; drain A(t+1) regs; write A(t+1); issue A(t+2)
        #pragma unroll
        for (int m = 0; m < 2; ++m)
            #pragma unroll
            for (int ks = 0; ks < 2; ++ks)
                af[m][ks] = ldsfrag(lds, buf * 3 + slotA, rA + m * 16 + fr, ks, cb0);
        #pragma unroll
        for (int n = 0; n < 2; ++n)
            #pragma unroll
            for (int ks = 0; ks < 2; ++ks)
                bv[n][ks] = ldsfrag(lds, buf * 3 + 2, rB + n * 16 + fr, ks, cb0);
        asm volatile("s_waitcnt vmcnt(2)" ::: "memory");
        WRITEA(nbuf)
        LOADA(k2)
        __builtin_amdgcn_s_barrier();
        __builtin_amdgcn_s_setprio(1);
        QUAD2(0, 0)
        __builtin_amdgcn_s_setprio(0);
        __builtin_amdgcn_s_barrier();

        // ph1: read bv23
        #pragma unroll
        for (int n = 2; n < 4; ++n)
            #pragma unroll
            for (int ks = 0; ks < 2; ++ks)
                bv[n][ks] = ldsfrag(lds, buf * 3 + 2, rB + n * 16 + fr, ks, cb0);
        __builtin_amdgcn_s_barrier();
        __builtin_amdgcn_s_setprio(1);
        QUAD2(0, 2)
        __builtin_amdgcn_s_setprio(0);
        __builtin_amdgcn_s_barrier();

        // ph2: read af23; stage (t+2).B
        #pragma unroll
        for (int m = 2; m < 4; ++m)
            #pragma unroll
            for (int ks = 0; ks < 2; ++ks)
                af[m][ks] = ldsfrag(lds, buf * 3 + slotA, rA + m * 16 + fr, ks, cb0);
        stage_half(lds, B, 1024, bcol, k2, buf * 3 + 2, tid);
        __builtin_amdgcn_s_barrier();
        __builtin_amdgcn_s_setprio(1);
        QUAD2(2, 2)
        __builtin_amdgcn_s_setprio(0);
        __builtin_amdgcn_s_barrier();

        // ph3: last quadrant; drain B(t+1); A ds_writes visible
        __builtin_amdgcn_s_setprio(1);
        QUAD2(2, 0)
        __builtin_amdgcn_s_setprio(0);
        asm volatile("s_waitcnt vmcnt(10)" ::: "memory");
        asm volatile("s_waitcnt lgkmcnt(0)" ::: "memory");
        __builtin_amdgcn_s_barrier();
    }
#undef QUAD2
#undef LOADA
#undef WRITEA

    #pragma unroll
    for (int mf = 0; mf < 4; ++mf) {
        const int r0 = brow + wm * 64 + mf * 16 + fq * 4;
        #pragma unroll
        for (int nf = 0; nf < 4; ++nf) {
            const int c = bcol + wn * 64 + nf * 16 + fr;
            #pragma unroll
            for (int j = 0; j < 4; ++j)
                C[(size_t)(r0 + j) * 1024 + c] = __float2bfloat16(acc[mf][nf][j]);
        }
    }
}

// ====== BM=256 x BN=128 GEMM, MODE 1 = scores (causal) ======
template<int MODE>
__launch_bounds__(512, 2)
__global__ void gemm_bn128(const bf16* __restrict__ A, const bf16* __restrict__ B,
                           bf16* __restrict__ Cb, float* __restrict__ Cf,
                           const bf16* __restrict__ Res,
                           int lda, int ldb, int ldc, int K,
                           long sA, long sB, long sC, long sR, float scale)
{
    extern __shared__ char lds[];
    int bi, bj;
    if (MODE == 1) { bj = blockIdx.x; bi = blockIdx.y; if (bj > 2 * bi + 1) return; }
    else           { bi = blockIdx.x; bj = blockIdx.y; }
    const int bz = blockIdx.z;
    A += (size_t)bz * sA;
    B += (size_t)bz * sB;
    const int brow = bi * 256, bcol = bj * 128;

    const int tid  = threadIdx.x;
    const int lane = tid & 63;
    const int w    = tid >> 6;
    const int wm   = w >> 1, wn = w & 1;
    const int fr   = lane & 15, fq = lane >> 4;
    const int cb0  = ((fr & 7) ^ fq) << 4;
    const int slotA = wm >> 1;
    const int rA    = (wm & 1) * 64;
    const int rB    = wn * 64;

    const int kmax = (MODE == 2) ? (brow + 256) : K;
    const int NT   = kmax >> 6;

    f32x4 acc[4][4] = {};
    bf16x8 af[4][2], bv[4][2];

    stage_half(lds, B, ldb, bcol,       0, 2, tid);
    stage_half(lds, A, lda, brow,       0, 0, tid);
    stage_half(lds, A, lda, brow + 128, 0, 1, tid);
    stage_half(lds, B, ldb, bcol,      64, 5, tid);
    asm volatile("s_waitcnt vmcnt(2)" ::: "memory");
    __builtin_amdgcn_s_barrier();

#define QUAD2(m0, n0)                                                         \
    _Pragma("unroll") for (int dm = 0; dm < 2; ++dm)                          \
    _Pragma("unroll") for (int dn = 0; dn < 2; ++dn)                          \
    _Pragma("unroll") for (int ks = 0; ks < 2; ++ks)                          \
        acc[(m0)+dm][(n0)+dn] = __builtin_amdgcn_mfma_f32_16x16x32_bf16(      \
            af[(m0)+dm][ks], bv[(n0)+dn][ks], acc[(m0)+dm][(n0)+dn], 0, 0, 0);

    for (int t = 0; t < NT; ++t) {
        const int buf = t & 1, nbuf = buf ^ 1;
        const int k1 = min(t + 1, NT - 1) << 6;
        const int k2 = min(t + 2, NT - 1) << 6;

        #pragma unroll
        for (int m = 0; m < 2; ++m)
            #pragma unroll
            for (int ks = 0; ks < 2; ++ks)
                af[m][ks] = ldsfrag(lds, buf * 3 + slotA, rA + m * 16 + fr, ks, cb0);
        #pragma unroll
        for (int n = 0; n < 2; ++n)
            #pragma unroll
            for (int ks = 0; ks < 2; ++ks)
                bv[n][ks] = ldsfrag(lds, buf * 3 + 2, rB + n * 16 + fr, ks, cb0);
        stage_half(lds, A, lda, brow, k1, nbuf * 3 + 0, tid);
        __builtin_amdgcn_s_barrier();
        __builtin_amdgcn_s_setprio(1);
        QUAD2(0, 0)
        __builtin_amdgcn_s_setprio(0);
        __builtin_amdgcn_s_barrier();

        #pragma unroll
        for (int n = 2; n < 4; ++n)
            #pragma unroll
            for (int ks = 0; ks < 2; ++ks)
                bv[n][ks] = ldsfrag(lds, buf * 3 + 2, rB + n * 16 + fr, ks, cb0);
        stage_half(lds, A, lda, brow + 128, k1, nbuf * 3 + 1, tid);
        __builtin_amdgcn_s_barrier();
        __builtin_amdgcn_s_setprio(1);
        QUAD2(0, 2)
        __builtin_amdgcn_s_setprio(0);
        __builtin_amdgcn_s_barrier();

        #pragma unroll
        for (int m = 2; m < 4; ++m)
            #pragma unroll
            for (int ks = 0; ks < 2; ++ks)
                af[m][ks] = ldsfrag(lds, buf * 3 + slotA, rA + m * 16 + fr, ks, cb0);
        stage_half(lds, B, ldb, bcol, k2, buf * 3 + 2, tid);
        __builtin_amdgcn_s_barrier();
        __builtin_amdgcn_s_setprio(1);
        QUAD2(2, 2)
        __builtin_amdgcn_s_setprio(0);
        __builtin_amdgcn_s_barrier();

        __builtin_amdgcn_s_setprio(1);
        QUAD2(2, 0)
        __builtin_amdgcn_s_setprio(0);
        asm volatile("s_waitcnt vmcnt(2)" ::: "memory");
        __builtin_amdgcn_s_barrier();
    }
#undef QUAD2

    if (MODE == 1) {
        bf16* Co = Cb + (size_t)bz * sC;
        #pragma unroll
        for (int mf = 0; mf < 4; ++mf) {
            const int r0 = brow + wm * 64 + mf * 16 + fq * 4;
            #pragma unroll
            for (int nf = 0; nf < 4; ++nf) {
                const int c = bcol + wn * 64 + nf * 16 + fr;
                #pragma unroll
                for (int j = 0; j < 4; ++j)
                    Co[(size_t)(r0 + j) * ldc + c] =
                        __float2bfloat16(acc[mf][nf][j] * scale);
            }
        }
    } else {
        float* Co = Cf + (size_t)bz * sC;
        const bf16* R = Res + (size_t)bz * sR;
        #pragma unroll
        for (int mf = 0; mf < 4; ++mf) {
            const int r0 = brow + wm * 64 + mf * 16 + fq * 4;
            #pragma unroll
            for (int nf = 0; nf < 4; ++nf) {
                const int c = bcol + wn * 64 + nf * 16 + fr;
                #pragma unroll
                for (int j = 0; j < 4; ++j)
                    Co[(size_t)(r0 + j) * ldc + c] = acc[mf][nf][j] +
                        __bfloat162float(R[(size_t)(r0 + j) * ldc + c]);
            }
        }
    }
}

// ====== PV: BM=128 x BN=128, causal-balanced pair (bi, 15-bi) per block ======
// LDS: A slots 0,1,2 (3-rotation) + B slots 3,4 (dbuf) = 80 KiB -> 2 blocks/CU.
// 8 waves 2Mx4N (wave tile 64x32), 2 phases/K-step, counted vmcnt(4).
__device__ __forceinline__ void pv_tile(char* lds, const bf16* P, const bf16* V,
                                        const bf16* R, float* C, int bi, int bcol,
                                        int tid, int wm, int wn, int fr, int fq,
                                        int cb0)
{
    const int brow = bi * 128;
    const int NT = 2 * (bi + 1);          // causal: K clipped to brow+128
    f32x4 acc[4][2] = {};
    bf16x8 af[4][2], bv[2][2];

    stage_half(lds, P, 2048, brow, 0,  0, tid);
    stage_half(lds, V, 2048, bcol, 0,  3, tid);
    stage_half(lds, P, 2048, brow, 64, 1, tid);
    stage_half(lds, V, 2048, bcol, 64, 4, tid);
    asm volatile("s_waitcnt vmcnt(4)" ::: "memory");
    __builtin_amdgcn_s_barrier();

    for (int t = 0; t < NT; ++t) {
        const int aslot = t % 3, bslot = 3 + (t & 1);
        const int k2 = min(t + 2, NT - 1) << 6;

        // ph0: read af01 + bv01; stage A(t+2) into free A slot
        #pragma unroll
        for (int m = 0; m < 2; ++m)
            #pragma unroll
            for (int ks = 0; ks < 2; ++ks)
                af[m][ks] = ldsfrag(lds, aslot, wm * 64 + m * 16 + fr, ks, cb0);
        #pragma unroll
        for (int n = 0; n < 2; ++n)
            #pragma unroll
            for (int ks = 0; ks < 2; ++ks)
                bv[n][ks] = ldsfrag(lds, bslot, wn * 32 + n * 16 + fr, ks, cb0);
        stage_half(lds, P, 2048, brow, k2, (t + 2) % 3, tid);
        __builtin_amdgcn_s_barrier();
        __builtin_amdgcn_s_setprio(1);
        #pragma unroll
        for (int m = 0; m < 2; ++m)
            #pragma unroll
            for (int n = 0; n < 2; ++n)
                #pragma unroll
                for (int ks = 0; ks < 2; ++ks)
                    acc[m][n] = __builtin_amdgcn_mfma_f32_16x16x32_bf16(
                        af[m][ks], bv[n][ks], acc[m][n], 0, 0, 0);
        __builtin_amdgcn_s_setprio(0);
        __builtin_amdgcn_s_barrier();

        // ph1: read af23; stage B(t+2) (current B slot, reads completed ph0)
        #pragma unroll
        for (int m = 2; m < 4; ++m)
            #pragma unroll
            for (int ks = 0; ks < 2; ++ks)
                af[m][ks] = ldsfrag(lds, aslot, wm * 64 + m * 16 + fr, ks, cb0);
        stage_half(lds, V, 2048, bcol, k2, bslot, tid);
        __builtin_amdgcn_s_barrier();
        __builtin_amdgcn_s_setprio(1);
        #pragma unroll
        for (int m = 2; m < 4; ++m)
            #pragma unroll
            for (int n = 0; n < 2; ++n)
                #pragma unroll
                for (int ks = 0; ks < 2; ++ks)
                    acc[m][n] = __builtin_amdgcn_mfma_f32_16x16x32_bf16(
                        af[m][ks], bv[n][ks], acc[m][n], 0, 0, 0);
        __builtin_amdgcn_s_setprio(0);
        asm volatile("s_waitcnt vmcnt(4)" ::: "memory");   // tile t+1 resident
        __builtin_amdgcn_s_barrier();
    }

    #pragma unroll
    for (int mf = 0; mf < 4; ++mf) {
        const int r0 = brow + wm * 64 + mf * 16 + fq * 4;
        #pragma unroll
        for (int nf = 0; nf < 2; ++nf) {
            const int c = bcol + wn * 32 + nf * 16 + fr;
            #pragma unroll
            for (int j = 0; j < 4; ++j)
                C[(size_t)(r0 + j) * 1024 + c] = acc[mf][nf][j] +
                    __bfloat162float(R[(size_t)(r0 + j) * 1024 + c]);
        }
    }
}

__launch_bounds__(512, 4)
__global__ void pv128(const bf16* __restrict__ P, const bf16* __restrict__ V,
                      const bf16* __restrict__ R, float* __restrict__ C)
{
    extern __shared__ char lds[];
    const int pid = blockIdx.x, bj = blockIdx.y, bz = blockIdx.z;
    const bf16* Pb = P + (size_t)bz * 2048 * 2048;
    const bf16* Vb = V + (size_t)bz * 1024 * 2048;
    const bf16* Rb = R + (size_t)bz * 2048 * 1024;
    float* Cb = C + (size_t)bz * 2048 * 1024;

    const int tid  = threadIdx.x;
    const int lane = tid & 63;
    const int w    = tid >> 6;
    const int wm   = w >> 2, wn = w & 3;      // 2M x 4N
    const int fr   = lane & 15, fq = lane >> 4;
    const int cb0  = ((fr & 7) ^ fq) << 4;
    const int bcol = bj * 128;

    pv_tile(lds, Pb, Vb, Rb, Cb, pid, bcol, tid, wm, wn, fr, fq, cb0);
    asm volatile("s_waitcnt vmcnt(0) lgkmcnt(0)" ::: "memory");
    __builtin_amdgcn_s_barrier();
    pv_tile(lds, Pb, Vb, Rb, Cb, 15 - pid, bcol, tid, wm, wn, fr, fq, cb0);
}

// Wt[n][k] = bf16(wi[k][n]),  1024x1024
__global__ void transpose_wi(const float* __restrict__ wi, bf16* __restrict__ Wt)
{
    __shared__ float t[32][33];
    const int n0 = blockIdx.x * 32, k0 = blockIdx.y * 32;
    const int lx = threadIdx.x & 31, ly = threadIdx.x >> 5;
    for (int i = ly; i < 32; i += 8)
        t[i][lx] = wi[(size_t)(k0 + i) * 1024 + n0 + lx];
    __syncthreads();
    for (int i = ly; i < 32; i += 8)
        Wt[(size_t)(n0 + i) * 1024 + k0 + lx] = __float2bfloat16(t[lx][i]);
}

// vpT[b][d][s] = vp[b][s][d]
__global__ void transpose_vp(const bf16* __restrict__ vp, bf16* __restrict__ vpT)
{
    __shared__ bf16 t[32][33];
    const int b = blockIdx.z;
    const int d0 = blockIdx.x * 32, s0 = blockIdx.y * 32;
    const bf16* src = vp + (size_t)b * 2048 * 1024;
    bf16* dst = vpT + (size_t)b * 1024 * 2048;
    const int lx = threadIdx.x & 31, ly = threadIdx.x >> 5;
    for (int i = ly; i < 32; i += 8)
        t[i][lx] = src[(size_t)(s0 + i) * 1024 + d0 + lx];
    __syncthreads();
    for (int i = ly; i < 32; i += 8)
        dst[(size_t)(d0 + i) * 2048 + s0 + lx] = t[lx][i];
}

// wave-per-row causal softmax, causal-bounded loads/stores
__launch_bounds__(256)
__global__ void softmax_rows(bf16* __restrict__ P)
{
    const int wid = threadIdx.x >> 6, lane = threadIdx.x & 63;
    const int r = blockIdx.x * 4 + wid, b = blockIdx.y;
    bf16* row = P + ((size_t)b * 2048 + r) * 2048;
    const int nv  = r + 1;
    const int rup = (r & ~255) + 256;

    float vals[4][8];
    float m = -1e30f;
    #pragma unroll
    for (int c = 0; c < 4; ++c) {
        const int k0 = c * 512 + lane * 8;
        if (k0 < rup) {
            bf16x8 x = *(const bf16x8*)(row + k0);
            #pragma unroll
            for (int j = 0; j < 8; ++j) {
                float f = (k0 + j < nv) ? bf2f(x[j]) : -1e30f;
                vals[c][j] = f;
                m = fmaxf(m, f);
            }
        } else {
            #pragma unroll
            for (int j = 0; j < 8; ++j) vals[c][j] = -1e30f;
        }
    }
    #pragma unroll
    for (int o = 32; o; o >>= 1) m = fmaxf(m, __shfl_xor(m, o));

    float sum = 0.f;
    #pragma unroll
    for (int c = 0; c < 4; ++c)
        #pragma unroll
        for (int j = 0; j < 8; ++j) {
            float e = __expf(vals[c][j] - m);
            vals[c][j] = e;
            sum += e;
        }
    #pragma unroll
    for (int o = 32; o; o >>= 1) sum += __shfl_xor(sum, o);
    const float inv = 1.0f / sum;

    #pragma unroll
    for (int c = 0; c < 4; ++c) {
        const int k0 = c * 512 + lane * 8;
        if (k0 < rup) {
            union { short h[8]; bf16x8 v8; } o;
            #pragma unroll
            for (int j = 0; j < 8; ++j) {
                bf16 hh = __float2bfloat16(vals[c][j] * inv);
                o.h[j] = *(short*)&hh;
            }
            *(bf16x8*)(row + k0) = o.v8;
        }
    }
}

extern "C" void kernel_launch(void* const* d_in, const int* in_sizes, int n_in,
                              void* d_out, int out_size, void* d_ws, size_t ws_size,
                              hipStream_t stream)
{
    const float* v  = (const float*)d_in[0];
    const float* k  = (const float*)d_in[1];
    const float* q  = (const float*)d_in[2];
    const float* wi = (const float*)d_in[3];
    float* out = (float*)d_out;

    char* ws = (char*)d_ws;
    const size_t WT_OFF   = 0;                       // 2 MB
    const size_t PROJ_OFF = WT_OFF + (2u << 20);     // 48 MB
    const size_t VPT_OFF  = PROJ_OFF + (size_t)24576 * 1024 * 2;   // 16 MB
    const size_t P_OFF    = VPT_OFF + (size_t)4 * 1024 * 2048 * 2; // 32 MB

    bf16* Wt   = (bf16*)(ws + WT_OFF);
    bf16* proj = (bf16*)(ws + PROJ_OFF);   // [q(8192)|k(8192)|v(8192)] x 1024
    bf16* vpT  = (bf16*)(ws + VPT_OFF);    // [4][1024][2048]
    bf16* P    = (bf16*)(ws + P_OFF);      // [4][2048][2048]

    bf16* qp_b = proj;
    bf16* kp_b = proj + (size_t)8192 * 1024;
    bf16* vp_b = proj + (size_t)16384 * 1024;

    (void)hipFuncSetAttribute((const void*)proj_fused,
            hipFuncAttributeMaxDynamicSharedMemorySize, 98304);
    (void)hipFuncSetAttribute((const void*)gemm_bn128<1>,
            hipFuncAttributeMaxDynamicSharedMemorySize, 98304);
    (void)hipFuncSetAttribute((const void*)pv128,
            hipFuncAttributeMaxDynamicSharedMemorySize, 81920);

    transpose_wi<<<dim3(32, 32), 256, 0, stream>>>(wi, Wt);

    // fused convert+projection (reads f32 q,k,v; reg-staged A, 4-phase cover)
    proj_fused<<<dim3(8, 96), 512, 98304, stream>>>(q, k, v, Wt, proj);

    transpose_vp<<<dim3(32, 64, 4), 256, 0, stream>>>(vp_b, vpT);

    // scores: per batch [2048,2048] = qp @ kp^T * 1/32, causal skip
    gemm_bn128<1><<<dim3(16, 8, 4), 512, 98304, stream>>>(
        qp_b, kp_b, P, nullptr, nullptr,
        1024, 1024, 2048, 1024,
        (long)2048 * 1024, (long)2048 * 1024, (long)2048 * 2048, 0, 0.03125f);

    softmax_rows<<<dim3(512, 4), 256, 0, stream>>>(P);

    // PV: causal-balanced pairs (bi, 15-bi), BM=128, 2 blocks/CU
    pv128<<<dim3(8, 8, 4), 512, 81920, stream>>>(P, vpT, qp_b, out);
}

// Round 7
// 183.735 us; speedup vs baseline: 1.2408x; 1.2408x over previous
//
#include <hip/hip_runtime.h>
#include <hip/hip_bf16.h>

typedef __hip_bfloat16 bf16;
typedef short bf16x8 __attribute__((ext_vector_type(8)));
typedef float f32x4 __attribute__((ext_vector_type(4)));

#define HT 16384   // bf16 half-tile bytes: 128 rows x 64 cols

__device__ __forceinline__ void gload16(const void* g, void* l) {
    __builtin_amdgcn_global_load_lds(
        (const __attribute__((address_space(1))) void*)g,
        (__attribute__((address_space(3))) void*)l, 16, 0, 0);
}

// Stage one 128x64 bf16 half-tile into LDS slot slotIdx (16 KiB units).
// Linear LDS dest; source pre-swizzled with involution chunk ^= row&7.
__device__ __forceinline__ void stage_half(char* lds, const bf16* src, int ld,
                                           int rowbase, int k0, int slotIdx,
                                           int tid)
{
    char* dst = lds + (size_t)slotIdx * HT + tid * 16;
    const int sub = tid >> 3;
    const int cb  = ((tid & 7) ^ (sub & 7)) << 4;
    #pragma unroll
    for (int p = 0; p < 2; ++p) {
        const int row = p * 64 + sub;
        const char* g = (const char*)(src + (size_t)(rowbase + row) * ld + k0) + cb;
        gload16(g, dst + p * 8192);
    }
}

// read one MFMA A/B fragment (8 bf16 = 16B) with the read-side swizzle
__device__ __forceinline__ bf16x8 ldsfrag(const char* lds, int slotIdx,
                                          int row, int ks, int cb0)
{
    return *(const bf16x8*)(lds + (size_t)slotIdx * HT
                            + row * 128 + (cb0 ^ (ks << 6)));
}

__device__ __forceinline__ float bf2f(short s) {
    union { float f; unsigned u; } c;
    c.u = ((unsigned)(unsigned short)s) << 16;
    return c.f;
}

// ====== projection: [24576,1024]bf16 = Xb @ Wt^T-form, BM=256 BN=128 ======
// 8 waves 4Mx2N (wave 64x64). LDS slots/buf: A0=0 A1=1 B=2; dbuf = 96 KiB.
// Grid 768 blocks = exactly 3 rounds of 256 CUs (zero tail); XCD-chunked.
__launch_bounds__(512, 2)
__global__ void proj_bn128(const bf16* __restrict__ A, const bf16* __restrict__ B,
                           bf16* __restrict__ C)
{
    extern __shared__ char lds[];
    const int orig = blockIdx.y * 8 + blockIdx.x;      // 768 blocks
    const int wk = (orig & 7) * 96 + (orig >> 3);      // bijective, 96/XCD
    const int bi = wk >> 3, bj = wk & 7;               // bi 0..95, bj 0..7
    const int brow = bi * 256, bcol = bj * 128;

    const int tid  = threadIdx.x;
    const int lane = tid & 63;
    const int w    = tid >> 6;
    const int wm   = w >> 1, wn = w & 1;
    const int fr   = lane & 15, fq = lane >> 4;
    const int cb0  = ((fr & 7) ^ fq) << 4;
    const int slotA = wm >> 1;
    const int rA    = (wm & 1) * 64;
    const int rB    = wn * 64;
    const int NT    = 16;                              // K=1024/64

    f32x4 acc[4][4] = {};
    bf16x8 af[4][2], bv[4][2];

    stage_half(lds, B, 1024, bcol,       0, 2, tid);
    stage_half(lds, A, 1024, brow,       0, 0, tid);
    stage_half(lds, A, 1024, brow + 128, 0, 1, tid);
    stage_half(lds, B, 1024, bcol,      64, 5, tid);
    asm volatile("s_waitcnt vmcnt(2)" ::: "memory");
    __builtin_amdgcn_s_barrier();

#define QUAD2(m0, n0)                                                         \
    _Pragma("unroll") for (int dm = 0; dm < 2; ++dm)                          \
    _Pragma("unroll") for (int dn = 0; dn < 2; ++dn)                          \
    _Pragma("unroll") for (int ks = 0; ks < 2; ++ks)                          \
        acc[(m0)+dm][(n0)+dn] = __builtin_amdgcn_mfma_f32_16x16x32_bf16(      \
            af[(m0)+dm][ks], bv[(n0)+dn][ks], acc[(m0)+dm][(n0)+dn], 0, 0, 0);

    for (int t = 0; t < NT; ++t) {
        const int buf = t & 1, nbuf = buf ^ 1;
        const int k1 = min(t + 1, NT - 1) << 6;
        const int k2 = min(t + 2, NT - 1) << 6;

        // ph0: read af01 + bv01; stage (t+1).A0
        #pragma unroll
        for (int m = 0; m < 2; ++m)
            #pragma unroll
            for (int ks = 0; ks < 2; ++ks)
                af[m][ks] = ldsfrag(lds, buf * 3 + slotA, rA + m * 16 + fr, ks, cb0);
        #pragma unroll
        for (int n = 0; n < 2; ++n)
            #pragma unroll
            for (int ks = 0; ks < 2; ++ks)
                bv[n][ks] = ldsfrag(lds, buf * 3 + 2, rB + n * 16 + fr, ks, cb0);
        stage_half(lds, A, 1024, brow, k1, nbuf * 3 + 0, tid);
        __builtin_amdgcn_s_barrier();
        __builtin_amdgcn_s_setprio(1);
        QUAD2(0, 0)
        __builtin_amdgcn_s_setprio(0);
        __builtin_amdgcn_s_barrier();

        // ph1: read bv23; stage (t+1).A1
        #pragma unroll
        for (int n = 2; n < 4; ++n)
            #pragma unroll
            for (int ks = 0; ks < 2; ++ks)
                bv[n][ks] = ldsfrag(lds, buf * 3 + 2, rB + n * 16 + fr, ks, cb0);
        stage_half(lds, A, 1024, brow + 128, k1, nbuf * 3 + 1, tid);
        __builtin_amdgcn_s_barrier();
        __builtin_amdgcn_s_setprio(1);
        QUAD2(0, 2)
        __builtin_amdgcn_s_setprio(0);
        __builtin_amdgcn_s_barrier();

        // ph2: read af23; stage (t+2).B
        #pragma unroll
        for (int m = 2; m < 4; ++m)
            #pragma unroll
            for (int ks = 0; ks < 2; ++ks)
                af[m][ks] = ldsfrag(lds, buf * 3 + slotA, rA + m * 16 + fr, ks, cb0);
        stage_half(lds, B, 1024, bcol, k2, buf * 3 + 2, tid);
        __builtin_amdgcn_s_barrier();
        __builtin_amdgcn_s_setprio(1);
        QUAD2(2, 2)
        __builtin_amdgcn_s_setprio(0);
        __builtin_amdgcn_s_barrier();

        // ph3: last quadrant; counted vmcnt leaves (t+2).B in flight
        __builtin_amdgcn_s_setprio(1);
        QUAD2(2, 0)
        __builtin_amdgcn_s_setprio(0);
        asm volatile("s_waitcnt vmcnt(2)" ::: "memory");
        __builtin_amdgcn_s_barrier();
    }
#undef QUAD2

    #pragma unroll
    for (int mf = 0; mf < 4; ++mf) {
        const int r0 = brow + wm * 64 + mf * 16 + fq * 4;
        #pragma unroll
        for (int nf = 0; nf < 4; ++nf) {
            const int c = bcol + wn * 64 + nf * 16 + fr;
            #pragma unroll
            for (int j = 0; j < 4; ++j)
                C[(size_t)(r0 + j) * 1024 + c] = __float2bfloat16(acc[mf][nf][j]);
        }
    }
}

// ====== 128x128 tile engine (2-phase, A 3-slot rotation + B dbuf, 80 KiB) ====
// 8 waves 2Mx4N (wave 64x32). MODE 1: Cb = scale*(A@B^T) bf16, ldc=ldcb.
// MODE 2: Cf = A@B^T + Res f32, ldc=ldcb.
template<int MODE>
__device__ __forceinline__ void tile128(char* lds, const bf16* A, const bf16* B,
                                        bf16* Cb, float* Cf, const bf16* Res,
                                        int lda, int ldb, int ldcb,
                                        int brow, int bcol, int NT, float scale,
                                        int tid, int wm, int wn, int fr, int fq,
                                        int cb0)
{
    f32x4 acc[4][2] = {};
    bf16x8 af[4][2], bv[2][2];

    stage_half(lds, A, lda, brow, 0,  0, tid);
    stage_half(lds, B, ldb, bcol, 0,  3, tid);
    stage_half(lds, A, lda, brow, 64, 1, tid);
    stage_half(lds, B, ldb, bcol, 64, 4, tid);
    asm volatile("s_waitcnt vmcnt(4)" ::: "memory");
    __builtin_amdgcn_s_barrier();

    for (int t = 0; t < NT; ++t) {
        const int aslot = t % 3, bslot = 3 + (t & 1);
        const int k2 = min(t + 2, NT - 1) << 6;

        // ph0: read af01 + bv01; stage A(t+2) into free A slot
        #pragma unroll
        for (int m = 0; m < 2; ++m)
            #pragma unroll
            for (int ks = 0; ks < 2; ++ks)
                af[m][ks] = ldsfrag(lds, aslot, wm * 64 + m * 16 + fr, ks, cb0);
        #pragma unroll
        for (int n = 0; n < 2; ++n)
            #pragma unroll
            for (int ks = 0; ks < 2; ++ks)
                bv[n][ks] = ldsfrag(lds, bslot, wn * 32 + n * 16 + fr, ks, cb0);
        stage_half(lds, A, lda, brow, k2, (t + 2) % 3, tid);
        __builtin_amdgcn_s_barrier();
        __builtin_amdgcn_s_setprio(1);
        #pragma unroll
        for (int m = 0; m < 2; ++m)
            #pragma unroll
            for (int n = 0; n < 2; ++n)
                #pragma unroll
                for (int ks = 0; ks < 2; ++ks)
                    acc[m][n] = __builtin_amdgcn_mfma_f32_16x16x32_bf16(
                        af[m][ks], bv[n][ks], acc[m][n], 0, 0, 0);
        __builtin_amdgcn_s_setprio(0);
        __builtin_amdgcn_s_barrier();

        // ph1: read af23; stage B(t+2) (reads of bslot completed in ph0)
        #pragma unroll
        for (int m = 2; m < 4; ++m)
            #pragma unroll
            for (int ks = 0; ks < 2; ++ks)
                af[m][ks] = ldsfrag(lds, aslot, wm * 64 + m * 16 + fr, ks, cb0);
        stage_half(lds, B, ldb, bcol, k2, bslot, tid);
        __builtin_amdgcn_s_barrier();
        __builtin_amdgcn_s_setprio(1);
        #pragma unroll
        for (int m = 2; m < 4; ++m)
            #pragma unroll
            for (int n = 0; n < 2; ++n)
                #pragma unroll
                for (int ks = 0; ks < 2; ++ks)
                    acc[m][n] = __builtin_amdgcn_mfma_f32_16x16x32_bf16(
                        af[m][ks], bv[n][ks], acc[m][n], 0, 0, 0);
        __builtin_amdgcn_s_setprio(0);
        asm volatile("s_waitcnt vmcnt(4)" ::: "memory");   // tile t+1 resident
        __builtin_amdgcn_s_barrier();
    }

    #pragma unroll
    for (int mf = 0; mf < 4; ++mf) {
        const int r0 = brow + wm * 64 + mf * 16 + fq * 4;
        #pragma unroll
        for (int nf = 0; nf < 2; ++nf) {
            const int c = bcol + wn * 32 + nf * 16 + fr;
            #pragma unroll
            for (int j = 0; j < 4; ++j) {
                if (MODE == 1)
                    Cb[(size_t)(r0 + j) * ldcb + c] =
                        __float2bfloat16(acc[mf][nf][j] * scale);
                else
                    Cf[(size_t)(r0 + j) * ldcb + c] = acc[mf][nf][j] +
                        __bfloat162float(Res[(size_t)(r0 + j) * ldcb + c]);
            }
        }
    }
}

// scores: triangular grid, per batch 136 tiles of 128x128; P = qp@kp^T * 1/32
__launch_bounds__(512, 4)
__global__ void scores128(const bf16* __restrict__ qp, const bf16* __restrict__ kp,
                          bf16* __restrict__ P)
{
    extern __shared__ char lds[];
    const int j = blockIdx.x;                     // 0..135
    int bi = (int)((__fsqrt_rn(8.0f * j + 1.0f) - 1.0f) * 0.5f);
    while ((bi + 1) * (bi + 2) / 2 <= j) ++bi;
    while (bi * (bi + 1) / 2 > j) --bi;
    const int bj = j - bi * (bi + 1) / 2;         // bj <= bi
    const int bz = blockIdx.z;

    const int tid  = threadIdx.x;
    const int lane = tid & 63;
    const int w    = tid >> 6;
    const int wm   = w >> 2, wn = w & 3;          // 2M x 4N
    const int fr   = lane & 15, fq = lane >> 4;
    const int cb0  = ((fr & 7) ^ fq) << 4;

    tile128<1>(lds,
               qp + (size_t)bz * 2048 * 1024,
               kp + (size_t)bz * 2048 * 1024,
               P + (size_t)bz * 2048 * 2048, nullptr, nullptr,
               1024, 1024, 2048,
               bi * 128, bj * 128, 16, 0.03125f,
               tid, wm, wn, fr, fq, cb0);
}

// PV: causal-balanced pair (bi, 15-bi) per block; O = P@vpT^T + qp residual
__launch_bounds__(512, 4)
__global__ void pv128(const bf16* __restrict__ P, const bf16* __restrict__ V,
                      const bf16* __restrict__ R, float* __restrict__ C)
{
    extern __shared__ char lds[];
    const int pid = blockIdx.x, bj = blockIdx.y, bz = blockIdx.z;
    const bf16* Pb = P + (size_t)bz * 2048 * 2048;
    const bf16* Vb = V + (size_t)bz * 1024 * 2048;
    const bf16* Rb = R + (size_t)bz * 2048 * 1024;
    float* Cb = C + (size_t)bz * 2048 * 1024;

    const int tid  = threadIdx.x;
    const int lane = tid & 63;
    const int w    = tid >> 6;
    const int wm   = w >> 2, wn = w & 3;          // 2M x 4N
    const int fr   = lane & 15, fq = lane >> 4;
    const int cb0  = ((fr & 7) ^ fq) << 4;
    const int bcol = bj * 128;

    tile128<2>(lds, Pb, Vb, nullptr, Cb, Rb, 2048, 2048, 1024,
               pid * 128, bcol, 2 * (pid + 1), 1.0f,
               tid, wm, wn, fr, fq, cb0);
    asm volatile("s_waitcnt vmcnt(0) lgkmcnt(0)" ::: "memory");
    __builtin_amdgcn_s_barrier();
    const int bi2 = 15 - pid;
    tile128<2>(lds, Pb, Vb, nullptr, Cb, Rb, 2048, 2048, 1024,
               bi2 * 128, bcol, 2 * (bi2 + 1), 1.0f,
               tid, wm, wn, fr, fq, cb0);
}

// fp32 -> bf16 convert of q,k,v into stacked [3*8192][1024], 16B stores
__global__ void convert_qkv(const float* __restrict__ q, const float* __restrict__ k,
                            const float* __restrict__ v, bf16* __restrict__ Xb)
{
    const int N8 = 8192 * 1024 / 8;
    const int total = 3 * N8;
    for (int i = blockIdx.x * 256 + threadIdx.x; i < total; i += gridDim.x * 256) {
        const int t = i / N8, j = i - t * N8;
        const float4* s = (t == 0) ? (const float4*)q
                        : (t == 1) ? (const float4*)k : (const float4*)v;
        float4 a = s[2 * j], bq = s[2 * j + 1];
        float vals[8] = {a.x, a.y, a.z, a.w, bq.x, bq.y, bq.z, bq.w};
        union { short h[8]; bf16x8 v8; } o;
        #pragma unroll
        for (int e = 0; e < 8; ++e) {
            bf16 hh = __float2bfloat16(vals[e]);
            o.h[e] = *(short*)&hh;
        }
        ((bf16x8*)Xb)[i] = o.v8;
    }
}

// Wt[n][k] = bf16(wi[k][n]),  1024x1024
__global__ void transpose_wi(const float* __restrict__ wi, bf16* __restrict__ Wt)
{
    __shared__ float t[32][33];
    const int n0 = blockIdx.x * 32, k0 = blockIdx.y * 32;
    const int lx = threadIdx.x & 31, ly = threadIdx.x >> 5;
    for (int i = ly; i < 32; i += 8)
        t[i][lx] = wi[(size_t)(k0 + i) * 1024 + n0 + lx];
    __syncthreads();
    for (int i = ly; i < 32; i += 8)
        Wt[(size_t)(n0 + i) * 1024 + k0 + lx] = __float2bfloat16(t[lx][i]);
}

// vpT[b][d][s] = vp[b][s][d]
__global__ void transpose_vp(const bf16* __restrict__ vp, bf16* __restrict__ vpT)
{
    __shared__ bf16 t[32][33];
    const int b = blockIdx.z;
    const int d0 = blockIdx.x * 32, s0 = blockIdx.y * 32;
    const bf16* src = vp + (size_t)b * 2048 * 1024;
    bf16* dst = vpT + (size_t)b * 1024 * 2048;
    const int lx = threadIdx.x & 31, ly = threadIdx.x >> 5;
    for (int i = ly; i < 32; i += 8)
        t[i][lx] = src[(size_t)(s0 + i) * 1024 + d0 + lx];
    __syncthreads();
    for (int i = ly; i < 32; i += 8)
        dst[(size_t)(d0 + i) * 2048 + s0 + lx] = t[lx][i];
}

// wave-per-row causal softmax, causal-bounded loads/stores
__launch_bounds__(256)
__global__ void softmax_rows(bf16* __restrict__ P)
{
    const int wid = threadIdx.x >> 6, lane = threadIdx.x & 63;
    const int r = blockIdx.x * 4 + wid, b = blockIdx.y;
    bf16* row = P + ((size_t)b * 2048 + r) * 2048;
    const int nv  = r + 1;
    const int rup = (r & ~255) + 256;

    float vals[4][8];
    float m = -1e30f;
    #pragma unroll
    for (int c = 0; c < 4; ++c) {
        const int k0 = c * 512 + lane * 8;
        if (k0 < rup) {
            bf16x8 x = *(const bf16x8*)(row + k0);
            #pragma unroll
            for (int j = 0; j < 8; ++j) {
                float f = (k0 + j < nv) ? bf2f(x[j]) : -1e30f;
                vals[c][j] = f;
                m = fmaxf(m, f);
            }
        } else {
            #pragma unroll
            for (int j = 0; j < 8; ++j) vals[c][j] = -1e30f;
        }
    }
    #pragma unroll
    for (int o = 32; o; o >>= 1) m = fmaxf(m, __shfl_xor(m, o));

    float sum = 0.f;
    #pragma unroll
    for (int c = 0; c < 4; ++c)
        #pragma unroll
        for (int j = 0; j < 8; ++j) {
            float e = __expf(vals[c][j] - m);
            vals[c][j] = e;
            sum += e;
        }
    #pragma unroll
    for (int o = 32; o; o >>= 1) sum += __shfl_xor(sum, o);
    const float inv = 1.0f / sum;

    #pragma unroll
    for (int c = 0; c < 4; ++c) {
        const int k0 = c * 512 + lane * 8;
        if (k0 < rup) {
            union { short h[8]; bf16x8 v8; } o;
            #pragma unroll
            for (int j = 0; j < 8; ++j) {
                bf16 hh = __float2bfloat16(vals[c][j] * inv);
                o.h[j] = *(short*)&hh;
            }
            *(bf16x8*)(row + k0) = o.v8;
        }
    }
}

extern "C" void kernel_launch(void* const* d_in, const int* in_sizes, int n_in,
                              void* d_out, int out_size, void* d_ws, size_t ws_size,
                              hipStream_t stream)
{
    const float* v  = (const float*)d_in[0];
    const float* k  = (const float*)d_in[1];
    const float* q  = (const float*)d_in[2];
    const float* wi = (const float*)d_in[3];
    float* out = (float*)d_out;

    char* ws = (char*)d_ws;
    const size_t WT_OFF   = 0;                       // 2 MB
    const size_t PROJ_OFF = WT_OFF + (2u << 20);     // 48 MB
    const size_t VPT_OFF  = PROJ_OFF + (size_t)24576 * 1024 * 2;   // 16 MB
    const size_t XB_OFF   = VPT_OFF + (size_t)4 * 1024 * 2048 * 2; // 48 MB

    bf16* Wt   = (bf16*)(ws + WT_OFF);
    bf16* proj = (bf16*)(ws + PROJ_OFF);   // [q(8192)|k(8192)|v(8192)] x 1024
    bf16* vpT  = (bf16*)(ws + VPT_OFF);    // [4][1024][2048]
    bf16* Xb   = (bf16*)(ws + XB_OFF);     // [24576][1024] bf16 X
    bf16* P    = Xb;                       // P [4][2048][2048] aliases Xb (dead)

    bf16* qp_b = proj;
    bf16* kp_b = proj + (size_t)8192 * 1024;
    bf16* vp_b = proj + (size_t)16384 * 1024;

    (void)hipFuncSetAttribute((const void*)proj_bn128,
            hipFuncAttributeMaxDynamicSharedMemorySize, 98304);
    (void)hipFuncSetAttribute((const void*)scores128,
            hipFuncAttributeMaxDynamicSharedMemorySize, 81920);
    (void)hipFuncSetAttribute((const void*)pv128,
            hipFuncAttributeMaxDynamicSharedMemorySize, 81920);

    transpose_wi<<<dim3(32, 32), 256, 0, stream>>>(wi, Wt);
    convert_qkv<<<2048, 256, 0, stream>>>(q, k, v, Xb);

    // projection: 768 blocks = 3 exact rounds, XCD-chunked
    proj_bn128<<<dim3(8, 96), 512, 98304, stream>>>(Xb, Wt, proj);

    transpose_vp<<<dim3(32, 64, 4), 256, 0, stream>>>(vp_b, vpT);

    // scores: triangular 136 tiles/batch, 128x128, 2 blocks/CU
    scores128<<<dim3(136, 1, 4), 512, 81920, stream>>>(qp_b, kp_b, P);

    softmax_rows<<<dim3(512, 4), 256, 0, stream>>>(P);

    // PV: causal-balanced pairs (bi, 15-bi), BM=128, 2 blocks/CU
    pv128<<<dim3(8, 8, 4), 512, 81920, stream>>>(P, vpT, qp_b, out);
}